// Round 11
// baseline (240.236 us; speedup 1.0000x reference)
//
#include <hip/hip_runtime.h>

typedef __attribute__((ext_vector_type(8))) short short8;
typedef __attribute__((ext_vector_type(4))) float float4v;

#define P1B   256    // bucketize chunk blocks (keeps all CUs in the role mix)
#define GS    256    // nodes per bucketize group: CH/G ~ 16 edges = 64B runs
#define GSH   8      // log2(GS)
#define CAPG  4608   // static gbuf slots per group; mean 4096, +8 sigma
#define AGS   32     // nodes per aggmm block (eighth-group filter)
#define ELCAP 768    // LDS edge slots per eighth-group; mean 512, +11 sigma
#define GCAP2 512    // max groups supported (N <= 131072)
#define MPAD  66     // mean_lds row pad (dwords): breaks row-stride bank conflict

__device__ __forceinline__ unsigned short f2bf(float f) {
    union { float f; unsigned u; } v; v.f = f;
    unsigned r = v.u + 0x7fffu + ((v.u >> 16) & 1u);   // round-to-nearest-even
    return (unsigned short)(r >> 16);
}
__device__ __forceinline__ float bf2f(unsigned short u) {
    union { unsigned u; float f; } v; v.u = ((unsigned)u) << 16; return v.f;
}

// ---------------- K1: fused [bucketize | LN+ReLU | W-prep], 1024 thr ----
// b < P1B:                 bucketize — LDS hist over 391 groups, run
//                          reservation via gcnt (static base g*CAPG),
//                          place packed edges in 64B full-line runs.
// P1B <= b < P1B+LNB16:    LayerNorm+ReLU, 16 rows/block (wave per row)
// else (4 blocks):         pack W fragments (MFMA B layout)
__global__ __launch_bounds__(1024) void pre_kernel(
    const float* __restrict__ x, const float* __restrict__ gamma,
    const float* __restrict__ beta, unsigned* __restrict__ hbuf,
    const int* __restrict__ idx, int* __restrict__ gcnt,
    int* __restrict__ gbuf, const float* __restrict__ Wl,
    const float* __restrict__ Wr, unsigned short* __restrict__ wsb,
    int N, int E, int LNB16, int G) {
    const int b = blockIdx.x, t = threadIdx.x;
    if (b < P1B) {
        __shared__ int hist[GCAP2], base[GCAP2];
        for (int i = t; i < G; i += 1024) hist[i] = 0;
        __syncthreads();
        const int CH = (E + P1B - 1) / P1B;    // 6250 <= 8*1024
        const int e0 = b * CH, e1 = min(E, e0 + CH);
        int dcache[8];                         // static-indexed dst cache
        #pragma unroll
        for (int k = 0; k < 8; k++) {
            const int e = e0 + t + k * 1024;
            const int d = (e < e1) ? idx[E + e] : -1;
            dcache[k] = d;
            if (d >= 0) atomicAdd(&hist[d >> GSH], 1);
        }
        __syncthreads();
        for (int i = t; i < G; i += 1024) {
            const int c = hist[i];
            base[i] = c ? (i * CAPG + atomicAdd(&gcnt[i], c)) : 0;
            hist[i] = 0;
        }
        __syncthreads();
        #pragma unroll
        for (int k = 0; k < 8; k++) {
            const int e = e0 + t + k * 1024;
            const int d = dcache[k];
            if (d >= 0) {
                const int src = idx[e];
                const int g = d >> GSH;
                const int pos = base[g] + atomicAdd(&hist[g], 1);
                if (pos < (g + 1) * CAPG)      // +8 sigma overflow guard
                    gbuf[pos] = (src << GSH) | (d & (GS - 1));
            }
        }
    } else if (b < P1B + LNB16) {
        const int row = (b - P1B) * 16 + (t >> 6);
        if (row >= N) return;
        const int lane = t & 63;
        const size_t bse = (size_t)row * 128 + lane * 2;
        float2 v = *(const float2*)&x[bse];
        float s = v.x + v.y;
        #pragma unroll
        for (int o = 32; o; o >>= 1) s += __shfl_xor(s, o, 64);
        const float mu = s * 0.0078125f;
        const float d0 = v.x - mu, d1 = v.y - mu;
        float ss = d0 * d0 + d1 * d1;
        #pragma unroll
        for (int o = 32; o; o >>= 1) ss += __shfl_xor(ss, o, 64);
        const float rs = rsqrtf(ss * 0.0078125f + 1e-5f);
        float2 g = *(const float2*)&gamma[lane * 2];
        float2 bb = *(const float2*)&beta[lane * 2];
        float h0 = fmaxf(fmaf(d0 * rs, g.x, bb.x), 0.f);
        float h1 = fmaxf(fmaf(d1 * rs, g.y, bb.y), 0.f);
        hbuf[(size_t)row * 64 + lane] = (unsigned)f2bf(h0) | ((unsigned)f2bf(h1) << 16);
    } else {
        const int s = (b - P1B - LNB16) * 1024 + t;  // 0..4095
        const int tc = s >> 9, c = (s >> 6) & 7, l = s & 63;
        const int n  = tc * 16 + (l & 15);
        const int k0 = c * 32 + ((l >> 4) & 3) * 8;
        const float* w = (k0 < 128) ? (Wl + (size_t)n * 128 + k0)
                                    : (Wr + (size_t)n * 128 + (k0 - 128));
        unsigned short tmp[8];
        #pragma unroll
        for (int j = 0; j < 8; j++) tmp[j] = f2bf(w[j]);
        *(short8*)&wsb[(size_t)s * 8] = *(short8*)tmp;
    }
}

// ---------------- K2: fused [counting-sort | gather | MFMA | epilogue] --
// r10-proven body; block = eighth-group: g = b>>3, oct = b&7, filter by
// bits [7:5] of dstrem. Gather + MFMA bodies byte-identical.
__global__ __launch_bounds__(256) void aggmm_kernel(
    const unsigned* __restrict__ hbuf, const int* __restrict__ gbuf,
    const int* __restrict__ gcnt, const unsigned short* __restrict__ wsb,
    const float* __restrict__ bl, const float* __restrict__ x,
    float* __restrict__ out, int N) {
    __shared__ int elds[ELCAP];                    // 3 KB sorted src
    __shared__ int hist[AGS], segstart[AGS], cur[AGS];
    __shared__ unsigned mean_lds[AGS][MPAD];       // 8.25 KB bf16-pair mean rows
    const int t = threadIdx.x, w = t >> 6, l = t & 63;
    const int b = blockIdx.x;
    const int g = b >> 3, oct = b & 7;
    const int n0 = b << 5;                         // = g*256 + oct*32
    const int e0 = g * CAPG;
    const int cnt = min(gcnt[g], CAPG);

    if (t < AGS) hist[t] = 0;
    __syncthreads();
    for (int i = t; i < cnt; i += 256) {
        const int r = gbuf[e0 + i] & (GS - 1);
        if ((r >> 5) == oct) atomicAdd(&hist[r & (AGS - 1)], 1);
    }
    __syncthreads();
    if (t < AGS) cur[t] = hist[t];
    __syncthreads();
    for (int off = 1; off < AGS; off <<= 1) {
        int u = (t < AGS && t >= off) ? cur[t - off] : 0;
        __syncthreads();
        if (t < AGS) cur[t] += u;
        __syncthreads();
    }
    if (t < AGS) { segstart[t] = cur[t] - hist[t]; cur[t] = segstart[t]; }
    __syncthreads();
    for (int i = t; i < cnt; i += 256) {
        const int pk = gbuf[e0 + i];
        const int r = pk & (GS - 1);
        if ((r >> 5) == oct) {
            const int pos = atomicAdd(&cur[r & (AGS - 1)], 1);
            if (pos < ELCAP) elds[pos] = pk >> GSH;
        }
    }
    __syncthreads();

    // gather: wave w owns nodes w*8..w*8+7 (register accumulate, 16-deep ILP)
    for (int i = 0; i < 8; i++) {
        const int ln = w * 8 + i;
        const int sp = segstart[ln];
        int dend = sp + hist[ln];
        if (dend > ELCAP) dend = ELCAP;
        float a0 = 0.f, a1 = 0.f;
        int j = sp;
        for (; j + 16 <= dend; j += 16) {
            unsigned p[16];
            #pragma unroll
            for (int k = 0; k < 16; k++)
                p[k] = hbuf[(size_t)elds[j + k] * 64 + l];  // uniform elds -> broadcast
            #pragma unroll
            for (int k = 0; k < 16; k++) {
                a0 += bf2f((unsigned short)(p[k] & 0xffffu));
                a1 += bf2f((unsigned short)(p[k] >> 16));
            }
        }
        if (j + 8 <= dend) {
            unsigned p[8];
            #pragma unroll
            for (int k = 0; k < 8; k++)
                p[k] = hbuf[(size_t)elds[j + k] * 64 + l];
            #pragma unroll
            for (int k = 0; k < 8; k++) {
                a0 += bf2f((unsigned short)(p[k] & 0xffffu));
                a1 += bf2f((unsigned short)(p[k] >> 16));
            }
            j += 8;
        }
        for (; j < dend; j++) {
            unsigned p = hbuf[(size_t)elds[j] * 64 + l];
            a0 += bf2f((unsigned short)(p & 0xffffu));
            a1 += bf2f((unsigned short)(p >> 16));
        }
        const int dv = hist[ln];
        const float inv = (dv > 0) ? 1.f / (float)dv : 0.f;  // same quantization as split
        mean_lds[ln][l] = (unsigned)f2bf(a0 * inv) | ((unsigned)f2bf(a1 * inv) << 16);
    }
    __syncthreads();

    // MFMA: wave w -> row-tile rt = w>>1 (16 rows), col-half chh = w&1 (64 cols)
    const int rt = w >> 1, chh = w & 1;
    const int r = l & 15, q = l >> 4;
    const int lrow = rt * 16 + r;
    const int arow = min(n0 + lrow, N - 1);
    short8 af[8];                          // A-frag: row=lane&15, k=(lane>>4)*8+j
    #pragma unroll
    for (int c = 0; c < 4; c++)            // mean part (K 0..127) from LDS
        af[c] = *(const short8*)&mean_lds[lrow][c * 16 + q * 4];
    const unsigned short* hp = (const unsigned short*)hbuf + (size_t)arow * 128 + q * 8;
    #pragma unroll
    for (int c = 0; c < 4; c++)            // h part (K 128..255) from global
        af[4 + c] = *(const short8*)(hp + c * 32);
    #pragma unroll
    for (int cc = 0; cc < 4; cc++) {       // 4 col-tiles of 16
        const int tc = chh * 4 + cc;
        float4v acc = {0.f, 0.f, 0.f, 0.f};
        const short8* bw = (const short8*)wsb + (size_t)tc * 512;
        #pragma unroll
        for (int c = 0; c < 8; c++)
            acc = __builtin_amdgcn_mfma_f32_16x16x32_bf16(af[c], bw[c * 64 + l], acc, 0, 0, 0);
        const int col = tc * 16 + r;
        const float blv = bl[col];
        #pragma unroll
        for (int rr = 0; rr < 4; rr++) {   // C/D: col=lane&15, row=(lane>>4)*4+rr
            const int row = n0 + rt * 16 + q * 4 + rr;
            if (row < N)
                out[(size_t)row * 128 + col] = acc[rr] + blv + x[(size_t)row * 128 + col];
        }
    }
}

extern "C" void kernel_launch(void* const* d_in, const int* in_sizes, int n_in,
                              void* d_out, int out_size, void* d_ws, size_t ws_size,
                              hipStream_t stream) {
    const float* x     = (const float*)d_in[0];
    const int*   ei    = (const int*)d_in[1];
    const float* gamma = (const float*)d_in[2];
    const float* beta  = (const float*)d_in[3];
    const float* Wl    = (const float*)d_in[4];
    const float* bl    = (const float*)d_in[5];
    const float* Wr    = (const float*)d_in[6];
    float* out = (float*)d_out;

    const int C = 128;
    const int N = in_sizes[0] / C;          // 100000
    const int E = in_sizes[1] / 2;          // 1600000
    const int G = (N + GS - 1) >> GSH;      // 391 groups

    char* ws = (char*)d_ws;
    size_t off = 0;
    unsigned* hbuf = (unsigned*)(ws + off); off += (size_t)N * 256;       // 25.6 MB bf16 h
    int* gbuf      = (int*)(ws + off);      off += (size_t)G * CAPG * 4;  // 7.2 MB packed edges
    int* gcnt      = (int*)(ws + off);      off += GCAP2 * 4;
    unsigned short* wsb = (unsigned short*)(ws + off);                    // 64 KB packed W

    const int LNB16 = (N + 15) / 16;        // 6250 LN blocks (16 rows each)

    hipMemsetAsync(gcnt, 0, (size_t)G * 4, stream);
    pre_kernel<<<P1B + LNB16 + 4, 1024, 0, stream>>>(
        x, gamma, beta, hbuf, ei, gcnt, gbuf, Wl, Wr, wsb, N, E, LNB16, G);
    aggmm_kernel<<<8 * G, 256, 0, stream>>>(hbuf, gbuf, gcnt, wsb, bl, x, out, N);
}

// Round 12
// 229.576 us; speedup vs baseline: 1.0464x; 1.0464x over previous
//
#include <hip/hip_runtime.h>

typedef __attribute__((ext_vector_type(8))) short short8;
typedef __attribute__((ext_vector_type(4))) float float4v;

#define P1B   256    // bucketize chunk blocks (keeps all CUs in the role mix)
#define GS    256    // nodes per bucketize group: CH/G ~ 16 edges = 64B runs
#define GSH   8      // log2(GS)
#define CAPG  4608   // static gbuf slots per group; mean 4096, +8 sigma
#define AGS   32     // nodes per aggmm block (eighth-group filter)
#define ELCAP 768    // LDS edge slots per eighth-group; mean 512, +11 sigma
#define GCAP2 512    // max groups supported (N <= 131072)
#define MPAD  66     // mean_lds row pad (dwords): breaks row-stride bank conflict

__device__ __forceinline__ unsigned short f2bf(float f) {
    union { float f; unsigned u; } v; v.f = f;
    unsigned r = v.u + 0x7fffu + ((v.u >> 16) & 1u);   // round-to-nearest-even
    return (unsigned short)(r >> 16);
}
__device__ __forceinline__ float bf2f(unsigned short u) {
    union { unsigned u; float f; } v; v.u = ((unsigned)u) << 16; return v.f;
}

// ---------------- K1: fused [bucketize | LN+ReLU | W-prep], 1024 thr ----
// (r11-proven: GS=256 gives 64B full-line scatter runs, -9us on pre)
__global__ __launch_bounds__(1024) void pre_kernel(
    const float* __restrict__ x, const float* __restrict__ gamma,
    const float* __restrict__ beta, unsigned* __restrict__ hbuf,
    const int* __restrict__ idx, int* __restrict__ gcnt,
    int* __restrict__ gbuf, const float* __restrict__ Wl,
    const float* __restrict__ Wr, unsigned short* __restrict__ wsb,
    int N, int E, int LNB16, int G) {
    const int b = blockIdx.x, t = threadIdx.x;
    if (b < P1B) {
        __shared__ int hist[GCAP2], base[GCAP2];
        for (int i = t; i < G; i += 1024) hist[i] = 0;
        __syncthreads();
        const int CH = (E + P1B - 1) / P1B;    // 6250 <= 8*1024
        const int e0 = b * CH, e1 = min(E, e0 + CH);
        int dcache[8];                         // static-indexed dst cache
        #pragma unroll
        for (int k = 0; k < 8; k++) {
            const int e = e0 + t + k * 1024;
            const int d = (e < e1) ? idx[E + e] : -1;
            dcache[k] = d;
            if (d >= 0) atomicAdd(&hist[d >> GSH], 1);
        }
        __syncthreads();
        for (int i = t; i < G; i += 1024) {
            const int c = hist[i];
            base[i] = c ? (i * CAPG + atomicAdd(&gcnt[i], c)) : 0;
            hist[i] = 0;
        }
        __syncthreads();
        #pragma unroll
        for (int k = 0; k < 8; k++) {
            const int e = e0 + t + k * 1024;
            const int d = dcache[k];
            if (d >= 0) {
                const int src = idx[e];
                const int g = d >> GSH;
                const int pos = base[g] + atomicAdd(&hist[g], 1);
                if (pos < (g + 1) * CAPG)      // +8 sigma overflow guard
                    gbuf[pos] = (src << GSH) | (d & (GS - 1));
            }
        }
    } else if (b < P1B + LNB16) {
        const int row = (b - P1B) * 16 + (t >> 6);
        if (row >= N) return;
        const int lane = t & 63;
        const size_t bse = (size_t)row * 128 + lane * 2;
        float2 v = *(const float2*)&x[bse];
        float s = v.x + v.y;
        #pragma unroll
        for (int o = 32; o; o >>= 1) s += __shfl_xor(s, o, 64);
        const float mu = s * 0.0078125f;
        const float d0 = v.x - mu, d1 = v.y - mu;
        float ss = d0 * d0 + d1 * d1;
        #pragma unroll
        for (int o = 32; o; o >>= 1) ss += __shfl_xor(ss, o, 64);
        const float rs = rsqrtf(ss * 0.0078125f + 1e-5f);
        float2 g = *(const float2*)&gamma[lane * 2];
        float2 bb = *(const float2*)&beta[lane * 2];
        float h0 = fmaxf(fmaf(d0 * rs, g.x, bb.x), 0.f);
        float h1 = fmaxf(fmaf(d1 * rs, g.y, bb.y), 0.f);
        hbuf[(size_t)row * 64 + lane] = (unsigned)f2bf(h0) | ((unsigned)f2bf(h1) << 16);
    } else {
        const int s = (b - P1B - LNB16) * 1024 + t;  // 0..4095
        const int tc = s >> 9, c = (s >> 6) & 7, l = s & 63;
        const int n  = tc * 16 + (l & 15);
        const int k0 = c * 32 + ((l >> 4) & 3) * 8;
        const float* w = (k0 < 128) ? (Wl + (size_t)n * 128 + k0)
                                    : (Wr + (size_t)n * 128 + (k0 - 128));
        unsigned short tmp[8];
        #pragma unroll
        for (int j = 0; j < 8; j++) tmp[j] = f2bf(w[j]);
        *(short8*)&wsb[(size_t)s * 8] = *(short8*)tmp;
    }
}

// ---------------- K2: fused [filter | sort | gather | MFMA | epilogue] --
// r11 front-end was 32 serial window iterations (2 passes x 4096/256
// scalar) -> +15us. New: ONE int4 pass (4 iterations) filters ~512
// edges into LDS escratch + hist; placement pass reads escratch from
// LDS (2 iterations). Gather + MFMA bodies byte-identical (proven).
__global__ __launch_bounds__(256) void aggmm_kernel(
    const unsigned* __restrict__ hbuf, const int* __restrict__ gbuf,
    const int* __restrict__ gcnt, const unsigned short* __restrict__ wsb,
    const float* __restrict__ bl, const float* __restrict__ x,
    float* __restrict__ out, int N) {
    __shared__ int escratch[ELCAP];                // 3 KB filtered (unsorted)
    __shared__ int elds[ELCAP];                    // 3 KB sorted src
    __shared__ int hist[AGS], segstart[AGS], cur[AGS];
    __shared__ unsigned mean_lds[AGS][MPAD];       // 8.25 KB bf16-pair mean rows
    __shared__ int nfilt;
    const int t = threadIdx.x, w = t >> 6, l = t & 63;
    const int b = blockIdx.x;
    const int g = b >> 3, oct = b & 7;
    const int n0 = b << 5;                         // = g*256 + oct*32
    const int e0 = g * CAPG;
    const int cnt = min(gcnt[g], CAPG);

    if (t < AGS) hist[t] = 0;
    if (t == 0) nfilt = 0;
    __syncthreads();

    // pass 1: single int4 window scan, filter into escratch + hist
    for (int i4 = t * 4; i4 < cnt; i4 += 1024) {   // e0, i4 both 16B-aligned
        const int4 q = *(const int4*)&gbuf[e0 + i4];
        {   const int pk = q.x, r = pk & (GS - 1);
            if ((r >> 5) == oct) {
                const int pos = atomicAdd(&nfilt, 1);
                if (pos < ELCAP) escratch[pos] = pk;
                atomicAdd(&hist[r & (AGS - 1)], 1);
            } }
        if (i4 + 1 < cnt) {
            const int pk = q.y, r = pk & (GS - 1);
            if ((r >> 5) == oct) {
                const int pos = atomicAdd(&nfilt, 1);
                if (pos < ELCAP) escratch[pos] = pk;
                atomicAdd(&hist[r & (AGS - 1)], 1);
            } }
        if (i4 + 2 < cnt) {
            const int pk = q.z, r = pk & (GS - 1);
            if ((r >> 5) == oct) {
                const int pos = atomicAdd(&nfilt, 1);
                if (pos < ELCAP) escratch[pos] = pk;
                atomicAdd(&hist[r & (AGS - 1)], 1);
            } }
        if (i4 + 3 < cnt) {
            const int pk = q.w, r = pk & (GS - 1);
            if ((r >> 5) == oct) {
                const int pos = atomicAdd(&nfilt, 1);
                if (pos < ELCAP) escratch[pos] = pk;
                atomicAdd(&hist[r & (AGS - 1)], 1);
            } }
    }
    __syncthreads();
    if (t < AGS) cur[t] = hist[t];
    __syncthreads();
    for (int off = 1; off < AGS; off <<= 1) {
        int u = (t < AGS && t >= off) ? cur[t - off] : 0;
        __syncthreads();
        if (t < AGS) cur[t] += u;
        __syncthreads();
    }
    if (t < AGS) { segstart[t] = cur[t] - hist[t]; cur[t] = segstart[t]; }
    __syncthreads();

    // pass 2: place from LDS escratch into sorted elds
    const int nf = min(nfilt, ELCAP);
    for (int i = t; i < nf; i += 256) {
        const int pk = escratch[i];
        const int pos = atomicAdd(&cur[pk & (AGS - 1)], 1);
        if (pos < ELCAP) elds[pos] = pk >> GSH;
    }
    __syncthreads();

    // gather: wave w owns nodes w*8..w*8+7 (register accumulate, 16-deep ILP)
    for (int i = 0; i < 8; i++) {
        const int ln = w * 8 + i;
        const int sp = segstart[ln];
        int dend = sp + hist[ln];
        if (dend > ELCAP) dend = ELCAP;
        float a0 = 0.f, a1 = 0.f;
        int j = sp;
        for (; j + 16 <= dend; j += 16) {
            unsigned p[16];
            #pragma unroll
            for (int k = 0; k < 16; k++)
                p[k] = hbuf[(size_t)elds[j + k] * 64 + l];  // uniform elds -> broadcast
            #pragma unroll
            for (int k = 0; k < 16; k++) {
                a0 += bf2f((unsigned short)(p[k] & 0xffffu));
                a1 += bf2f((unsigned short)(p[k] >> 16));
            }
        }
        if (j + 8 <= dend) {
            unsigned p[8];
            #pragma unroll
            for (int k = 0; k < 8; k++)
                p[k] = hbuf[(size_t)elds[j + k] * 64 + l];
            #pragma unroll
            for (int k = 0; k < 8; k++) {
                a0 += bf2f((unsigned short)(p[k] & 0xffffu));
                a1 += bf2f((unsigned short)(p[k] >> 16));
            }
            j += 8;
        }
        for (; j < dend; j++) {
            unsigned p = hbuf[(size_t)elds[j] * 64 + l];
            a0 += bf2f((unsigned short)(p & 0xffffu));
            a1 += bf2f((unsigned short)(p >> 16));
        }
        const int dv = hist[ln];
        const float inv = (dv > 0) ? 1.f / (float)dv : 0.f;  // same quantization as split
        mean_lds[ln][l] = (unsigned)f2bf(a0 * inv) | ((unsigned)f2bf(a1 * inv) << 16);
    }
    __syncthreads();

    // MFMA: wave w -> row-tile rt = w>>1 (16 rows), col-half chh = w&1 (64 cols)
    const int rt = w >> 1, chh = w & 1;
    const int r = l & 15, q = l >> 4;
    const int lrow = rt * 16 + r;
    const int arow = min(n0 + lrow, N - 1);
    short8 af[8];                          // A-frag: row=lane&15, k=(lane>>4)*8+j
    #pragma unroll
    for (int c = 0; c < 4; c++)            // mean part (K 0..127) from LDS
        af[c] = *(const short8*)&mean_lds[lrow][c * 16 + q * 4];
    const unsigned short* hp = (const unsigned short*)hbuf + (size_t)arow * 128 + q * 8;
    #pragma unroll
    for (int c = 0; c < 4; c++)            // h part (K 128..255) from global
        af[4 + c] = *(const short8*)(hp + c * 32);
    #pragma unroll
    for (int cc = 0; cc < 4; cc++) {       // 4 col-tiles of 16
        const int tc = chh * 4 + cc;
        float4v acc = {0.f, 0.f, 0.f, 0.f};
        const short8* bw = (const short8*)wsb + (size_t)tc * 512;
        #pragma unroll
        for (int c = 0; c < 8; c++)
            acc = __builtin_amdgcn_mfma_f32_16x16x32_bf16(af[c], bw[c * 64 + l], acc, 0, 0, 0);
        const int col = tc * 16 + r;
        const float blv = bl[col];
        #pragma unroll
        for (int rr = 0; rr < 4; rr++) {   // C/D: col=lane&15, row=(lane>>4)*4+rr
            const int row = n0 + rt * 16 + q * 4 + rr;
            if (row < N)
                out[(size_t)row * 128 + col] = acc[rr] + blv + x[(size_t)row * 128 + col];
        }
    }
}

extern "C" void kernel_launch(void* const* d_in, const int* in_sizes, int n_in,
                              void* d_out, int out_size, void* d_ws, size_t ws_size,
                              hipStream_t stream) {
    const float* x     = (const float*)d_in[0];
    const int*   ei    = (const int*)d_in[1];
    const float* gamma = (const float*)d_in[2];
    const float* beta  = (const float*)d_in[3];
    const float* Wl    = (const float*)d_in[4];
    const float* bl    = (const float*)d_in[5];
    const float* Wr    = (const float*)d_in[6];
    float* out = (float*)d_out;

    const int C = 128;
    const int N = in_sizes[0] / C;          // 100000
    const int E = in_sizes[1] / 2;          // 1600000
    const int G = (N + GS - 1) >> GSH;      // 391 groups

    char* ws = (char*)d_ws;
    size_t off = 0;
    unsigned* hbuf = (unsigned*)(ws + off); off += (size_t)N * 256;       // 25.6 MB bf16 h
    int* gbuf      = (int*)(ws + off);      off += (size_t)G * CAPG * 4;  // 7.2 MB packed edges
    int* gcnt      = (int*)(ws + off);      off += GCAP2 * 4;
    unsigned short* wsb = (unsigned short*)(ws + off);                    // 64 KB packed W

    const int LNB16 = (N + 15) / 16;        // 6250 LN blocks (16 rows each)

    hipMemsetAsync(gcnt, 0, (size_t)G * 4, stream);
    pre_kernel<<<P1B + LNB16 + 4, 1024, 0, stream>>>(
        x, gamma, beta, hbuf, ei, gcnt, gbuf, Wl, Wr, wsb, N, E, LNB16, G);
    aggmm_kernel<<<8 * G, 256, 0, stream>>>(hbuf, gbuf, gcnt, wsb, bl, x, out, N);
}